// Round 4
// baseline (1715.761 us; speedup 1.0000x reference)
//
#include <hip/hip_runtime.h>

typedef unsigned int u32;
typedef _Float16 f16;
typedef __attribute__((ext_vector_type(8))) _Float16 half8;
typedef __attribute__((ext_vector_type(4))) float floatx4;

// ------------- transpose + fp32->fp16: out[C][R] = (f16)in[R][C]^T -------
__global__ void transpose_w(const float* __restrict__ in, f16* __restrict__ out,
                            int R, int C) {
  __shared__ f16 t[32][33];
  const int bx = blockIdx.x * 32, by = blockIdx.y * 32;
  const int x = threadIdx.x, y0 = threadIdx.y;
  for (int y = y0; y < 32; y += 8)
    t[y][x] = (f16)in[(size_t)(by + y) * C + bx + x];
  __syncthreads();
  for (int y = y0; y < 32; y += 8)
    out[(size_t)(bx + y) * R + by + x] = t[x][y];
}

// ---------------- G1[b] = adj @ F[b]  (18x18 @ 18x1024), fp16 out -------
__global__ __launch_bounds__(256) void adjmix(const float* __restrict__ F,
                                              const float* __restrict__ adj,
                                              f16* __restrict__ G1) {
  __shared__ float adjs[324];
  for (int i = threadIdx.x; i < 324; i += 256) adjs[i] = adj[i];
  __syncthreads();
  const int d = blockIdx.x * 256 + threadIdx.x;
  const size_t base = (size_t)blockIdx.y * 18432;
  float f[18];
#pragma unroll
  for (int j = 0; j < 18; ++j) f[j] = F[base + j * 1024 + d];
#pragma unroll
  for (int i = 0; i < 18; ++i) {
    float a = 0.f;
#pragma unroll
    for (int j = 0; j < 18; ++j) a += adjs[i * 18 + j] * f[j];
    G1[base + i * 1024 + d] = (f16)a;
  }
}

// ---------------- C = A[M,K] @ Bt[N,K]^T, fp16 MFMA, m93 structure ------
// MODE 0: leaky-relu(0.2) epilogue.  MODE 1: plain.  Both store fp16.
template <int MODE>
__global__ __launch_bounds__(256) void gemm_bt(const f16* __restrict__ A,
                                               const f16* __restrict__ Bt,
                                               f16* __restrict__ C,
                                               int M, int N, int K) {
  __shared__ __align__(16) f16 As[128 * 64];
  __shared__ __align__(16) f16 Bs[128 * 64];
  const int tid = threadIdx.x;
  const int wave = tid >> 6, lane = tid & 63;
  const int quad = lane >> 4, lrow = lane & 15;
  const size_t m0 = (size_t)blockIdx.x * 128;
  const size_t n0 = (size_t)blockIdx.y * 128;
  const int wm = (wave & 1) * 64, wn = (wave >> 1) * 64;

  floatx4 acc[4][4];
#pragma unroll
  for (int i = 0; i < 4; ++i)
#pragma unroll
    for (int j = 0; j < 4; ++j) acc[i][j] = (floatx4){0.f, 0.f, 0.f, 0.f};

  for (int k0 = 0; k0 < K; k0 += 64) {
#pragma unroll
    for (int g = 0; g < 4; ++g) {
      const int e = g * 256 + tid;                 // element-group slot
      const int row = e >> 3, col = (e & 7) * 8;   // As/Bs row-major 128x64
      half8 va = *(const half8*)(A + (m0 + row) * K + k0 + col);
      half8 vb = *(const half8*)(Bt + (n0 + row) * K + k0 + col);
      *(half8*)(As + row * 64 + col) = va;
      *(half8*)(Bs + row * 64 + col) = vb;
    }
    __syncthreads();
#pragma unroll
    for (int s = 0; s < 2; ++s) {
      half8 a[4], b[4];
#pragma unroll
      for (int i = 0; i < 4; ++i)
        a[i] = *(const half8*)(As + (wm + i * 16 + lrow) * 64 + s * 32 + quad * 8);
#pragma unroll
      for (int j = 0; j < 4; ++j)
        b[j] = *(const half8*)(Bs + (wn + j * 16 + lrow) * 64 + s * 32 + quad * 8);
#pragma unroll
      for (int i = 0; i < 4; ++i)
#pragma unroll
        for (int j = 0; j < 4; ++j)
          acc[i][j] = __builtin_amdgcn_mfma_f32_16x16x32_f16(a[i], b[j], acc[i][j], 0, 0, 0);
    }
    __syncthreads();
  }

#pragma unroll
  for (int i = 0; i < 4; ++i) {
    const size_t rb = m0 + wm + i * 16 + quad * 4;
#pragma unroll
    for (int j = 0; j < 4; ++j) {
      const size_t cb = n0 + wn + j * 16 + lrow;
#pragma unroll
      for (int r = 0; r < 4; ++r) {
        float x = acc[i][j][r];
        if (MODE == 0) x = x > 0.f ? x : 0.2f * x;
        C[(rb + r) * N + cb] = (f16)x;
      }
    }
  }
}

// ---------------- fused attention + LN + heads, one block per batch -----
// scores = (F . H2^T) @ adj^T ; attn = softmax ; An = attn@F + F ; LN ; heads
__global__ __launch_bounds__(256) void fused_attn(
    const float* __restrict__ F, const float* __restrict__ adj,
    const f16* __restrict__ H2,
    const float* __restrict__ lnw, const float* __restrict__ lnb,
    const float* __restrict__ fcnw, const float* __restrict__ fcnb,
    const float* __restrict__ fcgw, const float* __restrict__ fcgb,
    float* __restrict__ out_node, float* __restrict__ out_graph) {
  __shared__ __align__(16) f16 Hs[18 * 1028];  // H2 tile, later An (fp16)
  __shared__ float Ts[18 * 19];       // T, then attn
  __shared__ float adjs[324];
  __shared__ float Msh[1024];

  const int tid = threadIdx.x;
  const int lane = tid & 63, wave = tid >> 6;
  const int b = blockIdx.x;
  const float* Fb = F + (size_t)b * 18432;
  const f16* Hb = H2 + (size_t)b * 18432;

  for (int i = tid; i < 324; i += 256) adjs[i] = adj[i];
  for (int i = tid; i < 9216; i += 256) {  // 18*1024 halves as uint pairs
    const int r = i >> 9, c = (i & 511) << 1;
    *(u32*)(&Hs[r * 1028 + c]) = *(const u32*)(Hb + r * 1024 + c);
  }
  __syncthreads();

  // T[n][j] = sum_d F[n,d] * H2[j,d] ; 81 2x2 tiles, one wave each
  for (int tile = wave; tile < 81; tile += 4) {
    const int n0 = (tile / 9) * 2, j0 = (tile % 9) * 2;
    float a00 = 0.f, a01 = 0.f, a10 = 0.f, a11 = 0.f;
    for (int k = 0; k < 16; ++k) {
      const int d = lane + k * 64;
      const float f0 = Fb[n0 * 1024 + d];
      const float f1 = Fb[n0 * 1024 + 1024 + d];
      const float x0 = (float)Hs[j0 * 1028 + d];
      const float x1 = (float)Hs[j0 * 1028 + 1028 + d];
      a00 += f0 * x0; a01 += f0 * x1; a10 += f1 * x0; a11 += f1 * x1;
    }
#pragma unroll
    for (int off = 32; off > 0; off >>= 1) {
      a00 += __shfl_xor(a00, off);
      a01 += __shfl_xor(a01, off);
      a10 += __shfl_xor(a10, off);
      a11 += __shfl_xor(a11, off);
    }
    if (lane == 0) {
      Ts[n0 * 19 + j0] = a00;      Ts[n0 * 19 + j0 + 1] = a01;
      Ts[n0 * 19 + 19 + j0] = a10; Ts[n0 * 19 + 19 + j0 + 1] = a11;
    }
  }
  __syncthreads();

  // S = T @ adj^T, row softmax -> attn (in-place in Ts)
  if (tid < 18) {
    float t[18], s[18];
#pragma unroll
    for (int j = 0; j < 18; ++j) t[j] = Ts[tid * 19 + j];
    float mx = -3.4e38f;
    for (int m = 0; m < 18; ++m) {
      float a = 0.f;
#pragma unroll
      for (int j = 0; j < 18; ++j) a += t[j] * adjs[m * 18 + j];
      s[m] = a; mx = fmaxf(mx, a);
    }
    float sum = 0.f;
    for (int m = 0; m < 18; ++m) { s[m] = __expf(s[m] - mx); sum += s[m]; }
    const float inv = 1.f / sum;
    for (int m = 0; m < 18; ++m) Ts[tid * 19 + m] = s[m] * inv;
  }
  __syncthreads();

  // An = attn@F + F  -> Hs (overwrites H2 tile)
  for (int d = tid; d < 1024; d += 256) {
    float f[18];
#pragma unroll
    for (int j = 0; j < 18; ++j) f[j] = Fb[j * 1024 + d];
#pragma unroll
    for (int i = 0; i < 18; ++i) {
      float a = f[i];
#pragma unroll
      for (int j = 0; j < 18; ++j) a += Ts[i * 19 + j] * f[j];
      Hs[i * 1028 + d] = (f16)a;
    }
  }
  __syncthreads();

  // LayerNorm per row (one wave per row)
  for (int r = wave; r < 18; r += 4) {
    float s = 0.f, ss = 0.f;
    for (int k = 0; k < 16; ++k) {
      const float v = (float)Hs[r * 1028 + lane + k * 64];
      s += v; ss += v * v;
    }
#pragma unroll
    for (int off = 32; off > 0; off >>= 1) {
      s += __shfl_xor(s, off); ss += __shfl_xor(ss, off);
    }
    const float mu = s * (1.f / 1024.f);
    const float rstd = rsqrtf(ss * (1.f / 1024.f) - mu * mu + 1e-5f);
    for (int k = 0; k < 16; ++k) {
      const int d = lane + k * 64;
      const float v = (float)Hs[r * 1028 + d];
      Hs[r * 1028 + d] = (f16)((v - mu) * rstd * lnw[d] + lnb[d]);
    }
  }
  __syncthreads();

  // column means (for graph head) + node head
  for (int d = tid; d < 1024; d += 256) {
    float a = 0.f;
#pragma unroll
    for (int i = 0; i < 18; ++i) a += (float)Hs[i * 1028 + d];
    Msh[d] = a * (1.f / 18.f);
  }
  for (int p = tid; p < 252; p += 256) {
    const int n = p / 14, c = p % 14;
    float a = fcnb[c];
    for (int d = 0; d < 1024; ++d)
      a += (float)Hs[n * 1028 + d] * fcnw[c * 1024 + d];
    out_node[(size_t)b * 252 + p] = a;
  }
  __syncthreads();
  // graph head
  if (tid < 14) {
    float a = fcgb[tid];
    for (int d = 0; d < 1024; ++d) a += Msh[d] * fcgw[tid * 1024 + d];
    out_graph[(size_t)b * 14 + tid] = a;
  }
}

extern "C" void kernel_launch(void* const* d_in, const int* in_sizes, int n_in,
                              void* d_out, int out_size, void* d_ws, size_t ws_size,
                              hipStream_t stream) {
  // Reference dtypes are float32 for ALL inputs and outputs.
  const float* F    = (const float*)d_in[0];
  const float* adj  = (const float*)d_in[1];
  const float* w1   = (const float*)d_in[2];
  const float* w2   = (const float*)d_in[3];
  const float* lnw  = (const float*)d_in[4];
  const float* lnb  = (const float*)d_in[5];
  const float* fcnw = (const float*)d_in[6];
  const float* fcnb = (const float*)d_in[7];
  const float* fcgw = (const float*)d_in[8];
  const float* fcgb = (const float*)d_in[9];

  // Chunked pipeline: 8 chunks of 256 batches. Workspace (~46 MB):
  //   [W2t 4MB][W1t 4MB][G1c 9.4MB][X1c 18.9MB][H2c 9.4MB]  (all fp16)
  const int CH = 256;                 // batches per chunk
  const int MC = CH * 18;             // 4608 rows = 36 tiles of 128
  char* ws = (char*)d_ws;
  f16* W2t = (f16*)ws;
  f16* W1t = (f16*)(ws + (size_t)(4 << 20));
  f16* G1c = (f16*)(ws + (size_t)(8 << 20));
  f16* X1c = (f16*)(ws + (size_t)(8 << 20) + (size_t)MC * 1024 * 2);
  f16* H2c = (f16*)(ws + (size_t)(8 << 20) + (size_t)MC * 1024 * 2 +
                    (size_t)MC * 2048 * 2);

  float* out_node  = (float*)d_out;
  float* out_graph = out_node + (size_t)2048 * 18 * 14;

  // weight transposes (so GEMM B-fragments are k-contiguous), fp32->fp16
  transpose_w<<<dim3(2048 / 32, 1024 / 32), dim3(32, 8), 0, stream>>>(w1, W1t, 1024, 2048);
  transpose_w<<<dim3(1024 / 32, 2048 / 32), dim3(32, 8), 0, stream>>>(w2, W2t, 2048, 1024);

  for (int c = 0; c < 2048 / CH; ++c) {
    const float* Fc = F + (size_t)c * CH * 18432;
    // G1c = adj @ Fc (per batch)
    adjmix<<<dim3(4, CH), 256, 0, stream>>>(Fc, adj, G1c);
    // X1c = leaky(G1c @ W1)
    gemm_bt<0><<<dim3(MC / 128, 16), 256, 0, stream>>>(G1c, W1t, X1c,
                                                       MC, 2048, 1024);
    // H2c = X1c @ W2
    gemm_bt<1><<<dim3(MC / 128, 8), 256, 0, stream>>>(X1c, W2t, H2c,
                                                      MC, 1024, 2048);
    // attention + LN + heads
    fused_attn<<<CH, 256, 0, stream>>>(Fc, adj, H2c, lnw, lnb, fcnw, fcnb,
                                       fcgw, fcgb,
                                       out_node + (size_t)c * CH * 252,
                                       out_graph + (size_t)c * CH * 14);
  }
}

// Round 5
// 1442.224 us; speedup vs baseline: 1.1897x; 1.1897x over previous
//
#include <hip/hip_runtime.h>

typedef unsigned int u32;
typedef _Float16 f16;
typedef __attribute__((ext_vector_type(8))) _Float16 half8;
typedef __attribute__((ext_vector_type(4))) _Float16 half4;
typedef __attribute__((ext_vector_type(4))) float floatx4;

// ------------- transpose + fp32->fp16: out[C][R] = (f16)in[R][C]^T -------
__global__ void transpose_w(const float* __restrict__ in, f16* __restrict__ out,
                            int R, int C) {
  __shared__ f16 t[32][33];
  const int bx = blockIdx.x * 32, by = blockIdx.y * 32;
  const int x = threadIdx.x, y0 = threadIdx.y;
  for (int y = y0; y < 32; y += 8)
    t[y][x] = (f16)in[(size_t)(by + y) * C + bx + x];
  __syncthreads();
  for (int y = y0; y < 32; y += 8)
    out[(size_t)(bx + y) * R + by + x] = t[x][y];
}

// ---------------- G1[b] = adj @ F[b]  (18x18 @ 18x1024), fp16 out -------
__global__ __launch_bounds__(256) void adjmix(const float* __restrict__ F,
                                              const float* __restrict__ adj,
                                              f16* __restrict__ G1) {
  __shared__ float adjs[324];
  for (int i = threadIdx.x; i < 324; i += 256) adjs[i] = adj[i];
  __syncthreads();
  const int d = blockIdx.x * 256 + threadIdx.x;
  const size_t base = (size_t)blockIdx.y * 18432;
  float f[18];
#pragma unroll
  for (int j = 0; j < 18; ++j) f[j] = F[base + j * 1024 + d];
#pragma unroll
  for (int i = 0; i < 18; ++i) {
    float a = 0.f;
#pragma unroll
    for (int j = 0; j < 18; ++j) a += adjs[i * 18 + j] * f[j];
    G1[base + i * 1024 + d] = (f16)a;
  }
}

// ---------------- C = A[M,K] @ Bt[N,K]^T, fp16 MFMA, m97 structure ------
// async global->LDS staging (width 16). MODE 0: leaky-relu(0.2). MODE 1: plain.
template <int MODE>
__global__ __launch_bounds__(256) void gemm_bt(const f16* __restrict__ A,
                                               const f16* __restrict__ Bt,
                                               f16* __restrict__ C,
                                               int M, int N, int K) {
  __shared__ __align__(16) f16 As[128 * 64];
  __shared__ __align__(16) f16 Bs[128 * 64];
  const int tid = threadIdx.x;
  const int wave = tid >> 6, lane = tid & 63;
  const int quad = lane >> 4, lrow = lane & 15;
  const size_t m0 = (size_t)blockIdx.x * 128;
  const size_t n0 = (size_t)blockIdx.y * 128;
  const int wm = (wave & 1) * 64, wn = (wave >> 1) * 64;

  floatx4 acc[4][4];
#pragma unroll
  for (int i = 0; i < 4; ++i)
#pragma unroll
    for (int j = 0; j < 4; ++j) acc[i][j] = (floatx4){0.f, 0.f, 0.f, 0.f};

  for (int k0 = 0; k0 < K; k0 += 64) {
#pragma unroll
    for (int g = 0; g < 4; ++g) {
      const int e = g * 256 + tid;                  // element-group slot
      const int ldsoff = (g * 256 + wave * 64) * 8; // wave-uniform base (f16 elems)
      const f16* ga = A + (m0 + (e >> 3)) * K + k0 + (e & 7) * 8;
      __builtin_amdgcn_global_load_lds(
          (const __attribute__((address_space(1))) void*)ga,
          (__attribute__((address_space(3))) void*)(As + ldsoff), 16, 0, 0);
      const f16* gb = Bt + (n0 + (e >> 3)) * K + k0 + (e & 7) * 8;
      __builtin_amdgcn_global_load_lds(
          (const __attribute__((address_space(1))) void*)gb,
          (__attribute__((address_space(3))) void*)(Bs + ldsoff), 16, 0, 0);
    }
    __syncthreads();
#pragma unroll
    for (int s = 0; s < 2; ++s) {
      half8 a[4], b[4];
#pragma unroll
      for (int i = 0; i < 4; ++i)
        a[i] = *(const half8*)(As + (wm + i * 16 + lrow) * 64 + s * 32 + quad * 8);
#pragma unroll
      for (int j = 0; j < 4; ++j)
        b[j] = *(const half8*)(Bs + (wn + j * 16 + lrow) * 64 + s * 32 + quad * 8);
#pragma unroll
      for (int i = 0; i < 4; ++i)
#pragma unroll
        for (int j = 0; j < 4; ++j)
          acc[i][j] = __builtin_amdgcn_mfma_f32_16x16x32_f16(a[i], b[j], acc[i][j], 0, 0, 0);
    }
    __syncthreads();
  }

#pragma unroll
  for (int i = 0; i < 4; ++i) {
    const size_t rb = m0 + wm + i * 16 + quad * 4;
#pragma unroll
    for (int j = 0; j < 4; ++j) {
      const size_t cb = n0 + wn + j * 16 + lrow;
#pragma unroll
      for (int r = 0; r < 4; ++r) {
        float x = acc[i][j][r];
        if (MODE == 0) x = x > 0.f ? x : 0.2f * x;
        C[(rb + r) * N + cb] = (f16)x;
      }
    }
  }
}

// ---------------- fused attention + LN + heads, one block per batch -----
// scores = (F . H2^T) @ adj^T ; attn = softmax ; An = attn@F + F ; LN ; heads
#define HP 1032  // Hs row pitch (f16 elems): 16B-aligned rows, bank-stride 4
__global__ __launch_bounds__(256, 3) void fused_attn(
    const float* __restrict__ F, const float* __restrict__ adj,
    const f16* __restrict__ H2,
    const float* __restrict__ lnw, const float* __restrict__ lnb,
    const float* __restrict__ fcnw, const float* __restrict__ fcnb,
    const float* __restrict__ fcgw, const float* __restrict__ fcgb,
    float* __restrict__ out_node, float* __restrict__ out_graph) {
  __shared__ __align__(16) f16 Hs[18 * HP];  // H2 tile, later An (fp16)
  __shared__ float Ts[18 * 19];              // T, then attn
  __shared__ float adjs[324];
  __shared__ float Msh[1024];

  const int tid = threadIdx.x;
  const int lane = tid & 63, wave = tid >> 6;
  const int b = blockIdx.x;
  const float* Fb = F + (size_t)b * 18432;
  const f16* Hb = H2 + (size_t)b * 18432;

  for (int i = tid; i < 324; i += 256) adjs[i] = adj[i];
  for (int i = tid; i < 2304; i += 256) {  // 18 rows x 128 half8 groups
    const int r = i >> 7, g = i & 127;
    *(half8*)(Hs + r * HP + g * 8) = *(const half8*)(Hb + r * 1024 + g * 8);
  }
  __syncthreads();

  // T[n][j] = sum_d F[n,d]*H2[j,d] ; 81 2x2 tiles, one wave each; f32x4/f16x4
  const floatx4* F4 = (const floatx4*)Fb;
  for (int tile = wave; tile < 81; tile += 4) {
    const int n0 = (tile / 9) * 2, j0 = (tile % 9) * 2;
    float a00 = 0.f, a01 = 0.f, a10 = 0.f, a11 = 0.f;
#pragma unroll
    for (int k = 0; k < 4; ++k) {
      const int d4 = k * 64 + lane;
      floatx4 f0 = F4[n0 * 256 + d4];
      floatx4 f1 = F4[n0 * 256 + 256 + d4];
      half4 x0 = *(const half4*)(Hs + j0 * HP + d4 * 4);
      half4 x1 = *(const half4*)(Hs + (j0 + 1) * HP + d4 * 4);
#pragma unroll
      for (int t = 0; t < 4; ++t) {
        a00 += f0[t] * (float)x0[t]; a01 += f0[t] * (float)x1[t];
        a10 += f1[t] * (float)x0[t]; a11 += f1[t] * (float)x1[t];
      }
    }
#pragma unroll
    for (int off = 32; off > 0; off >>= 1) {
      a00 += __shfl_xor(a00, off);
      a01 += __shfl_xor(a01, off);
      a10 += __shfl_xor(a10, off);
      a11 += __shfl_xor(a11, off);
    }
    if (lane == 0) {
      Ts[n0 * 19 + j0] = a00;      Ts[n0 * 19 + j0 + 1] = a01;
      Ts[n0 * 19 + 19 + j0] = a10; Ts[n0 * 19 + 19 + j0 + 1] = a11;
    }
  }
  __syncthreads();

  // S = T @ adj^T, row softmax -> attn (in-place in Ts)
  if (tid < 18) {
    float t[18], s[18];
#pragma unroll
    for (int j = 0; j < 18; ++j) t[j] = Ts[tid * 19 + j];
    float mx = -3.4e38f;
    for (int m = 0; m < 18; ++m) {
      float a = 0.f;
#pragma unroll
      for (int j = 0; j < 18; ++j) a += t[j] * adjs[m * 18 + j];
      s[m] = a; mx = fmaxf(mx, a);
    }
    float sum = 0.f;
    for (int m = 0; m < 18; ++m) { s[m] = __expf(s[m] - mx); sum += s[m]; }
    const float inv = 1.f / sum;
    for (int m = 0; m < 18; ++m) Ts[tid * 19 + m] = s[m] * inv;
  }
  __syncthreads();

  // An = attn@F + F  -> Hs (overwrites H2 tile)
  for (int d = tid; d < 1024; d += 256) {
    float f[18];
#pragma unroll
    for (int j = 0; j < 18; ++j) f[j] = Fb[j * 1024 + d];
#pragma unroll
    for (int i = 0; i < 18; ++i) {
      float a = f[i];
#pragma unroll
      for (int j = 0; j < 18; ++j) a += Ts[i * 19 + j] * f[j];
      Hs[i * HP + d] = (f16)a;
    }
  }
  __syncthreads();

  // LayerNorm per row (one wave per row), half4/float4
  for (int r = wave; r < 18; r += 4) {
    float s = 0.f, ss = 0.f;
#pragma unroll
    for (int k = 0; k < 4; ++k) {
      half4 v = *(const half4*)(Hs + r * HP + (k * 64 + lane) * 4);
#pragma unroll
      for (int t = 0; t < 4; ++t) { float x = (float)v[t]; s += x; ss += x * x; }
    }
#pragma unroll
    for (int off = 32; off > 0; off >>= 1) {
      s += __shfl_xor(s, off); ss += __shfl_xor(ss, off);
    }
    const float mu = s * (1.f / 1024.f);
    const float rstd = rsqrtf(ss * (1.f / 1024.f) - mu * mu + 1e-5f);
#pragma unroll
    for (int k = 0; k < 4; ++k) {
      const int d4 = k * 64 + lane;
      half4 v = *(const half4*)(Hs + r * HP + d4 * 4);
      floatx4 w = *(const floatx4*)(lnw + d4 * 4);
      floatx4 bb = *(const floatx4*)(lnb + d4 * 4);
      half4 o;
#pragma unroll
      for (int t = 0; t < 4; ++t)
        o[t] = (f16)(((float)v[t] - mu) * rstd * w[t] + bb[t]);
      *(half4*)(Hs + r * HP + d4 * 4) = o;
    }
  }
  __syncthreads();

  // column means (for graph head)
  for (int d = tid; d < 1024; d += 256) {
    float a = 0.f;
#pragma unroll
    for (int i = 0; i < 18; ++i) a += (float)Hs[i * HP + d];
    Msh[d] = a * (1.f / 18.f);
  }
  // node head: 252 dots of 1024, half8 x 2*float4
  const floatx4* fw4 = (const floatx4*)fcnw;
  for (int p = tid; p < 252; p += 256) {
    const int n = p / 14, c = p % 14;
    float acc = fcnb[c];
    for (int d8 = 0; d8 < 128; ++d8) {
      half8 h = *(const half8*)(Hs + n * HP + d8 * 8);
      floatx4 w0 = fw4[c * 256 + d8 * 2];
      floatx4 w1 = fw4[c * 256 + d8 * 2 + 1];
      acc += (float)h[0] * w0[0] + (float)h[1] * w0[1] + (float)h[2] * w0[2] +
             (float)h[3] * w0[3] + (float)h[4] * w1[0] + (float)h[5] * w1[1] +
             (float)h[6] * w1[2] + (float)h[7] * w1[3];
    }
    out_node[(size_t)b * 252 + p] = acc;
  }
  __syncthreads();
  // graph head
  if (tid < 14) {
    float acc = fcgb[tid];
    const floatx4* gw4 = (const floatx4*)fcgw;
    const floatx4* m4 = (const floatx4*)Msh;
    for (int q = 0; q < 256; ++q) {
      floatx4 w = gw4[tid * 256 + q];
      floatx4 m = m4[q];
      acc += m[0] * w[0] + m[1] * w[1] + m[2] * w[2] + m[3] * w[3];
    }
    out_graph[(size_t)b * 14 + tid] = acc;
  }
}

extern "C" void kernel_launch(void* const* d_in, const int* in_sizes, int n_in,
                              void* d_out, int out_size, void* d_ws, size_t ws_size,
                              hipStream_t stream) {
  const float* F    = (const float*)d_in[0];
  const float* adj  = (const float*)d_in[1];
  const float* w1   = (const float*)d_in[2];
  const float* w2   = (const float*)d_in[3];
  const float* lnw  = (const float*)d_in[4];
  const float* lnb  = (const float*)d_in[5];
  const float* fcnw = (const float*)d_in[6];
  const float* fcnb = (const float*)d_in[7];
  const float* fcgw = (const float*)d_in[8];
  const float* fcgb = (const float*)d_in[9];

  float* out_node  = (float*)d_out;
  float* out_graph = out_node + (size_t)2048 * 18 * 14;

  char* ws = (char*)d_ws;
  f16* W2t = (f16*)ws;                               // 4 MiB
  f16* W1t = (f16*)(ws + (size_t)(4 << 20));         // 4 MiB
  char* p8 = ws + (size_t)(8 << 20);

  // weight transposes (k-contiguous B fragments), fp32->fp16
  transpose_w<<<dim3(2048 / 32, 1024 / 32), dim3(32, 8), 0, stream>>>(w1, W1t, 1024, 2048);
  transpose_w<<<dim3(1024 / 32, 2048 / 32), dim3(32, 8), 0, stream>>>(w2, W2t, 2048, 1024);

  const size_t G1_FULL = 75497472ull;   // 36864*1024*2
  const size_t X1_FULL = 150994944ull;  // 36864*2048*2
  const size_t NEED_A = (size_t)(8 << 20) + G1_FULL + X1_FULL;             // ~224 MiB
  const size_t NEED_B = (size_t)(8 << 20) + G1_FULL + 9437184ull + 18874368ull; // ~107 MiB

  if (ws_size >= NEED_A) {
    // Plan A: full batch, 4 launches. H2 aliases G1 (dead after GEMM1).
    f16* G1 = (f16*)p8;
    f16* H2 = (f16*)p8;
    f16* X1 = (f16*)(p8 + G1_FULL);
    adjmix<<<dim3(4, 2048), 256, 0, stream>>>(F, adj, G1);
    gemm_bt<0><<<dim3(288, 16), 256, 0, stream>>>(G1, W1t, X1, 36864, 2048, 1024);
    gemm_bt<1><<<dim3(288, 8), 256, 0, stream>>>(X1, W2t, H2, 36864, 1024, 2048);
    fused_attn<<<2048, 256, 0, stream>>>(F, adj, H2, lnw, lnb, fcnw, fcnb,
                                         fcgw, fcgb, out_node, out_graph);
  } else if (ws_size >= NEED_B) {
    // Plan B: chunked GEMMs, full H2, single wide fused_attn.
    const int CH = 256, MC = CH * 18;
    f16* H2 = (f16*)p8;
    f16* G1c = (f16*)(p8 + G1_FULL);
    f16* X1c = (f16*)(p8 + G1_FULL + 9437184ull);
    for (int c = 0; c < 8; ++c) {
      const float* Fc = F + (size_t)c * CH * 18432;
      adjmix<<<dim3(4, CH), 256, 0, stream>>>(Fc, adj, G1c);
      gemm_bt<0><<<dim3(MC / 128, 16), 256, 0, stream>>>(G1c, W1t, X1c, MC, 2048, 1024);
      gemm_bt<1><<<dim3(MC / 128, 8), 256, 0, stream>>>(X1c, W2t,
                                                        H2 + (size_t)c * MC * 1024,
                                                        MC, 1024, 2048);
    }
    fused_attn<<<2048, 256, 0, stream>>>(F, adj, H2, lnw, lnb, fcnw, fcnb,
                                         fcgw, fcgb, out_node, out_graph);
  } else {
    // Plan C: fully chunked (44 MiB floor, known-good from round 4).
    const int CH = 256, MC = CH * 18;
    f16* G1c = (f16*)p8;
    f16* X1c = (f16*)(p8 + 9437184ull);
    f16* H2c = (f16*)(p8 + 9437184ull + 18874368ull);
    for (int c = 0; c < 8; ++c) {
      const float* Fc = F + (size_t)c * CH * 18432;
      adjmix<<<dim3(4, CH), 256, 0, stream>>>(Fc, adj, G1c);
      gemm_bt<0><<<dim3(MC / 128, 16), 256, 0, stream>>>(G1c, W1t, X1c, MC, 2048, 1024);
      gemm_bt<1><<<dim3(MC / 128, 8), 256, 0, stream>>>(X1c, W2t, H2c, MC, 1024, 2048);
      fused_attn<<<CH, 256, 0, stream>>>(Fc, adj, H2c, lnw, lnb, fcnw, fcnb,
                                         fcgw, fcgb,
                                         out_node + (size_t)c * CH * 252,
                                         out_graph + (size_t)c * CH * 14);
    }
  }
}